// Round 3
// baseline (342.754 us; speedup 1.0000x reference)
//
#include <hip/hip_runtime.h>
#include <math.h>
#include <stdint.h>

// FlowAttention B=4, L=S=4096, H=16, D=64 fp32.
// P1 ksum(K) -> P2 qsum,qn(Q) -> P3 kn,den,KV-partials via MFMA (K,V) -> reduce -> P4 out via MFMA (Q).
// GEMM-shaped contractions use bf16 hi/lo-split MFMA (3 mfma per tile-step, ~2^-16 rel err).
// R3 (bisect): DPP row-sums + 2x2 wave tiling + manual-unroll register double-buffer
// with PLAIN loads and __syncthreads only. No inline-asm loads / raw barriers / counted
// vmcnt (R2's abort suspects) -- single risky subsystem = DPP.
#define B_ 4
#define L_ 4096
#define H_ 16
#define EPSF 1e-6f
#define STR 66   // k_kv LDS row stride (words)
#define STRO 68  // k_out LDS row stride (words, 16B-aligned rows)

typedef short bf16x8 __attribute__((ext_vector_type(8)));
typedef float f32x4 __attribute__((ext_vector_type(4)));
union FragU { uint32_t u[4]; bf16x8 v; };

__device__ __forceinline__ float sigf(float x) { return 1.0f / (1.0f + __expf(-x)); }

// sum over each 16-lane row: quad xor1, quad xor2, row_ror:4, row_ror:8 (all full-rate VALU)
__device__ __forceinline__ float rowsum16(float v) {
    v += __int_as_float(__builtin_amdgcn_update_dpp(0, __float_as_int(v), 0xB1, 0xF, 0xF, true));
    v += __int_as_float(__builtin_amdgcn_update_dpp(0, __float_as_int(v), 0x4E, 0xF, 0xF, true));
    v += __int_as_float(__builtin_amdgcn_update_dpp(0, __float_as_int(v), 0x124, 0xF, 0xF, true));
    v += __int_as_float(__builtin_amdgcn_update_dpp(0, __float_as_int(v), 0x128, 0xF, 0xF, true));
    return v;
}

// pack fp32 -> (bf16 hi | bf16 lo) in one 32-bit word. hi = truncate-to-bf16, lo = x - hi.
__device__ __forceinline__ uint32_t packhl(float x) {
    uint32_t xb = __float_as_uint(x);
    uint32_t hb = xb & 0xFFFF0000u;
    float lo = x - __uint_as_float(hb);
    return (hb >> 16) | (__float_as_uint(lo) & 0xFFFF0000u);
}

// 8 packed words (k-order) -> hi and lo bf16x8 fragments via v_perm
__device__ __forceinline__ void buildfrag(const uint32_t w[8], bf16x8& hi, bf16x8& lo) {
    FragU H, L;
#pragma unroll
    for (int t = 0; t < 4; ++t) {
        H.u[t] = __builtin_amdgcn_perm(w[2 * t + 1], w[2 * t], 0x05040100u);
        L.u[t] = __builtin_amdgcn_perm(w[2 * t + 1], w[2 * t], 0x07060302u);
    }
    hi = H.v; lo = L.v;
}

#define MFMA3(acc, ahi, alo, bhi, blo)                                        \
    acc = __builtin_amdgcn_mfma_f32_16x16x32_bf16(ahi, bhi, acc, 0, 0, 0);    \
    acc = __builtin_amdgcn_mfma_f32_16x16x32_bf16(ahi, blo, acc, 0, 0, 0);    \
    acc = __builtin_amdgcn_mfma_f32_16x16x32_bf16(alo, bhi, acc, 0, 0, 0);

// ---------------- P1: ksum[d] = sum_s sigmoid(K) ----------------
__global__ __launch_bounds__(256, 6) void k_ksum(const float* __restrict__ K,
                                                 float* __restrict__ ksum) {
    int bh = blockIdx.x, b = bh >> 4, h = bh & 15;
    int t = threadIdx.x, lane = t & 63, w = t >> 6;
    int q4 = lane >> 4, i16 = lane & 15;
    int r0 = blockIdx.y * 128 + w * 32;
    float4 x[8];
#pragma unroll
    for (int j = 0; j < 8; ++j) {
        int r = r0 + j * 4 + q4;
        x[j] = *(const float4*)(K + (((size_t)b * L_ + r) * H_ + h) * 64 + 4 * i16);
    }
    float a0 = 0.f, a1 = 0.f, a2 = 0.f, a3 = 0.f;
#pragma unroll
    for (int j = 0; j < 8; ++j) {
        a0 += sigf(x[j].x); a1 += sigf(x[j].y);
        a2 += sigf(x[j].z); a3 += sigf(x[j].w);
    }
#pragma unroll
    for (int m = 16; m < 64; m <<= 1) {
        a0 += __shfl_xor(a0, m, 64); a1 += __shfl_xor(a1, m, 64);
        a2 += __shfl_xor(a2, m, 64); a3 += __shfl_xor(a3, m, 64);
    }
    if (q4 == 0) {
        atomicAdd(&ksum[bh * 64 + 4 * i16 + 0], a0);
        atomicAdd(&ksum[bh * 64 + 4 * i16 + 1], a1);
        atomicAdd(&ksum[bh * 64 + 4 * i16 + 2], a2);
        atomicAdd(&ksum[bh * 64 + 4 * i16 + 3], a3);
    }
}

// ---------------- P2: qsum[d], qn[d] ----------------
__global__ __launch_bounds__(256, 6) void k_qpass(const float* __restrict__ Q,
                                                  const float* __restrict__ ksum,
                                                  float* __restrict__ qsum,
                                                  float* __restrict__ qn) {
    int bh = blockIdx.x, b = bh >> 4, h = bh & 15;
    int t = threadIdx.x, lane = t & 63, w = t >> 6;
    int q4 = lane >> 4, i16 = lane & 15;
    int r0 = blockIdx.y * 128 + w * 32;
    float4 ks4 = *(const float4*)(ksum + bh * 64 + 4 * i16);
    ks4.x += EPSF; ks4.y += EPSF; ks4.z += EPSF; ks4.w += EPSF;
    float4 x[8];
#pragma unroll
    for (int j = 0; j < 8; ++j) {
        int r = r0 + j * 4 + q4;
        x[j] = *(const float4*)(Q + (((size_t)b * L_ + r) * H_ + h) * 64 + 4 * i16);
    }
    float qs0 = 0.f, qs1 = 0.f, qs2 = 0.f, qs3 = 0.f;
    float qa0 = 0.f, qa1 = 0.f, qa2 = 0.f, qa3 = 0.f;
#pragma unroll
    for (int j = 0; j < 8; ++j) {
        float s0 = sigf(x[j].x), s1 = sigf(x[j].y), s2 = sigf(x[j].z), s3 = sigf(x[j].w);
        float pa = (s0 + EPSF) * ks4.x + (s1 + EPSF) * ks4.y +
                   (s2 + EPSF) * ks4.z + (s3 + EPSF) * ks4.w;
        pa = rowsum16(pa);
        float nr = __builtin_amdgcn_rcpf(pa);
        qs0 += s0; qs1 += s1; qs2 += s2; qs3 += s3;
        qa0 += s0 * nr; qa1 += s1 * nr; qa2 += s2 * nr; qa3 += s3 * nr;
    }
#pragma unroll
    for (int m = 16; m < 64; m <<= 1) {
        qs0 += __shfl_xor(qs0, m, 64); qs1 += __shfl_xor(qs1, m, 64);
        qs2 += __shfl_xor(qs2, m, 64); qs3 += __shfl_xor(qs3, m, 64);
        qa0 += __shfl_xor(qa0, m, 64); qa1 += __shfl_xor(qa1, m, 64);
        qa2 += __shfl_xor(qa2, m, 64); qa3 += __shfl_xor(qa3, m, 64);
    }
    if (q4 == 0) {
        atomicAdd(&qsum[bh * 64 + 4 * i16 + 0], qs0);
        atomicAdd(&qsum[bh * 64 + 4 * i16 + 1], qs1);
        atomicAdd(&qsum[bh * 64 + 4 * i16 + 2], qs2);
        atomicAdd(&qsum[bh * 64 + 4 * i16 + 3], qs3);
        atomicAdd(&qn[bh * 64 + 4 * i16 + 0], qa0);
        atomicAdd(&qn[bh * 64 + 4 * i16 + 1], qa1);
        atomicAdd(&qn[bh * 64 + 4 * i16 + 2], qa2);
        atomicAdd(&qn[bh * 64 + 4 * i16 + 3], qa3);
    }
}

// ---- k_kv helpers ----
__device__ __forceinline__ void kv_load(const float* Kp, const float* Vp,
                                        int rowbase, int tile, int lrow,
                                        float4* kx, float4* vx) {
#pragma unroll
    for (int j = 0; j < 4; ++j) {
        size_t r = (size_t)(rowbase + tile * 64 + lrow + j * 4) * 1024;
        kx[j] = *(const float4*)(Kp + r);
        vx[j] = *(const float4*)(Vp + r);
    }
}

__device__ __forceinline__ void kv_stage(const float4* kx, const float4* vx,
                                         int w, int q4, int i16,
                                         float4 qsE, float4 qnE,
                                         uint32_t* skp, uint32_t* vwp,
                                         float& kn0, float& kn1, float& kn2, float& kn3,
                                         float& dacc) {
#pragma unroll
    for (int j = 0; j < 4; ++j) {
        int lr = w * 16 + j * 4 + q4;
        float s0 = sigf(kx[j].x), s1 = sigf(kx[j].y), s2 = sigf(kx[j].z), s3 = sigf(kx[j].w);
        float pa = (s0 + EPSF) * qsE.x + (s1 + EPSF) * qsE.y +
                   (s2 + EPSF) * qsE.z + (s3 + EPSF) * qsE.w;
        float pc = (s0 + EPSF) * qnE.x + (s1 + EPSF) * qnE.y +
                   (s2 + EPSF) * qnE.z + (s3 + EPSF) * qnE.w;
        pa = rowsum16(pa); pc = rowsum16(pc);
        float ncol = __builtin_amdgcn_rcpf(pa);
        float es = __expf(pc);                 // logits O(1): no max-subtract needed
        kn0 += s0 * ncol; kn1 += s1 * ncol; kn2 += s2 * ncol; kn3 += s3 * ncol;
        if (i16 == 0) dacc += es;
        uint32_t* sp = &skp[lr * STR + 4 * i16];
        *(uint2*)sp = make_uint2(packhl(s0), packhl(s1));
        *(uint2*)(sp + 2) = make_uint2(packhl(s2), packhl(s3));
        uint32_t* vp = &vwp[lr * STR + 4 * i16];
        *(uint2*)vp = make_uint2(packhl(vx[j].x * es), packhl(vx[j].y * es));
        *(uint2*)(vp + 2) = make_uint2(packhl(vx[j].z * es), packhl(vx[j].w * es));
    }
}

__device__ __forceinline__ void kv_mfma(const uint32_t* skp, const uint32_t* vwp,
                                        int q4, int i16, int td0, int te0, f32x4* acc) {
#pragma unroll
    for (int ks = 0; ks < 2; ++ks) {
        bf16x8 bhi[2], blo[2];
#pragma unroll
        for (int tn = 0; tn < 2; ++tn) {
            uint32_t bw[8];
#pragma unroll
            for (int j = 0; j < 8; ++j)
                bw[j] = vwp[(32 * ks + 8 * q4 + j) * STR + 16 * (te0 + tn) + i16];
            buildfrag(bw, bhi[tn], blo[tn]);
        }
#pragma unroll
        for (int tm = 0; tm < 2; ++tm) {
            uint32_t aw[8];
#pragma unroll
            for (int j = 0; j < 8; ++j)
                aw[j] = skp[(32 * ks + 8 * q4 + j) * STR + 16 * (td0 + tm) + i16];
            bf16x8 ahi, alo; buildfrag(aw, ahi, alo);
#pragma unroll
            for (int tn = 0; tn < 2; ++tn) {
                MFMA3(acc[tm * 2 + tn], ahi, alo, bhi[tn], blo[tn]);
            }
        }
    }
}

// ---------------- P3: kn, den, KV-partials via MFMA ----------------
__global__ __launch_bounds__(256, 4) void k_kv(const float* __restrict__ K,
                                               const float* __restrict__ V,
                                               const float* __restrict__ qsum,
                                               const float* __restrict__ qn,
                                               float* __restrict__ kn,
                                               float* __restrict__ den,
                                               float* __restrict__ KVp) {
    int bh = blockIdx.x, b = bh >> 4, h = bh & 15;
    int t = threadIdx.x, lane = t & 63, w = t >> 6;
    int q4 = lane >> 4, i16 = lane & 15;
    int td0 = (w >> 1) * 2, te0 = (w & 1) * 2;   // 2x2 output tiles per wave
    __shared__ uint32_t skp[64 * STR];
    __shared__ uint32_t vwp[64 * STR];
    float4 qsE = *(const float4*)(qsum + bh * 64 + 4 * i16);
    float4 qnE = *(const float4*)(qn + bh * 64 + 4 * i16);
    qsE.x += EPSF; qsE.y += EPSF; qsE.z += EPSF; qsE.w += EPSF;
    qnE.x += EPSF; qnE.y += EPSF; qnE.z += EPSF; qnE.w += EPSF;
    f32x4 acc[4];
#pragma unroll
    for (int tm = 0; tm < 4; ++tm) acc[tm] = (f32x4){0.f, 0.f, 0.f, 0.f};
    float kn0 = 0.f, kn1 = 0.f, kn2 = 0.f, kn3 = 0.f, dacc = 0.f;
    int rowbase = blockIdx.y * 256;
    size_t base = (((size_t)b * L_) * H_ + h) * 64 + 4 * i16;
    const float* Kp = K + base;
    const float* Vp = V + base;
    int lrow = w * 16 + q4;   // this lane's first staged row offset within a tile

    float4 kA[4], vA[4], kB[4], vB[4];
    // manual unroll, alternating buffers: next tile's loads issued BEFORE consuming
    // the current buffer. __syncthreads() bounds scheduling regions, so loads cannot
    // be sunk past the barrier (R1's discard bug cannot recur).
    kv_load(Kp, Vp, rowbase, 0, lrow, kA, vA);
    // tile 0
    kv_load(Kp, Vp, rowbase, 1, lrow, kB, vB);
    kv_stage(kA, vA, w, q4, i16, qsE, qnE, skp, vwp, kn0, kn1, kn2, kn3, dacc);
    __syncthreads();
    kv_mfma(skp, vwp, q4, i16, td0, te0, acc);
    __syncthreads();
    // tile 1
    kv_load(Kp, Vp, rowbase, 2, lrow, kA, vA);
    kv_stage(kB, vB, w, q4, i16, qsE, qnE, skp, vwp, kn0, kn1, kn2, kn3, dacc);
    __syncthreads();
    kv_mfma(skp, vwp, q4, i16, td0, te0, acc);
    __syncthreads();
    // tile 2
    kv_load(Kp, Vp, rowbase, 3, lrow, kB, vB);
    kv_stage(kA, vA, w, q4, i16, qsE, qnE, skp, vwp, kn0, kn1, kn2, kn3, dacc);
    __syncthreads();
    kv_mfma(skp, vwp, q4, i16, td0, te0, acc);
    __syncthreads();
    // tile 3
    kv_stage(kB, vB, w, q4, i16, qsE, qnE, skp, vwp, kn0, kn1, kn2, kn3, dacc);
    __syncthreads();
    kv_mfma(skp, vwp, q4, i16, td0, te0, acc);

    // ---- KV partial: plain stores (no atomics); slice = blockIdx.y
    // D[m=d][n=e], row=(lane>>4)*4+reg, col=lane&15 (m89-verified)
    float* kvslice = KVp + ((size_t)blockIdx.y * 64 + bh) * 4096;
#pragma unroll
    for (int tm = 0; tm < 2; ++tm)
#pragma unroll
        for (int tn = 0; tn < 2; ++tn)
#pragma unroll
            for (int r = 0; r < 4; ++r)
                kvslice[(16 * (td0 + tm) + 4 * q4 + r) * 64 + 16 * (te0 + tn) + i16] =
                    acc[tm * 2 + tn][r];
#pragma unroll
    for (int m = 16; m < 64; m <<= 1) {
        kn0 += __shfl_xor(kn0, m, 64); kn1 += __shfl_xor(kn1, m, 64);
        kn2 += __shfl_xor(kn2, m, 64); kn3 += __shfl_xor(kn3, m, 64);
    }
    if (q4 == 0) {
        atomicAdd(&kn[bh * 64 + 4 * i16 + 0], kn0);
        atomicAdd(&kn[bh * 64 + 4 * i16 + 1], kn1);
        atomicAdd(&kn[bh * 64 + 4 * i16 + 2], kn2);
        atomicAdd(&kn[bh * 64 + 4 * i16 + 3], kn3);
    }
#pragma unroll
    for (int m = 1; m < 64; m <<= 1) dacc += __shfl_xor(dacc, m, 64);
    if (lane == 0) atomicAdd(&den[bh], dacc);
}

// ---------------- P3b: KVg = sum over 16 partial slices ----------------
__global__ __launch_bounds__(256) void k_reduce(const float* __restrict__ KVp,
                                                float* __restrict__ KVg) {
    int bh = blockIdx.x;            // 64
    int f4 = blockIdx.y * 256 + threadIdx.x;  // float4 index in [0,1024)
    float4 acc = make_float4(0.f, 0.f, 0.f, 0.f);
#pragma unroll
    for (int p = 0; p < 16; ++p) {
        float4 x = *(const float4*)(KVp + ((size_t)p * 64 + bh) * 4096 + 4 * f4);
        acc.x += x.x; acc.y += x.y; acc.z += x.z; acc.w += x.w;
    }
    *(float4*)(KVg + (size_t)bh * 4096 + 4 * f4) = acc;
}

// ---- k_out helpers ----
__device__ __forceinline__ void out_stage(const float4* qx, int w, int q4, int i16,
                                          float4 ksE, float4 knE, float sden,
                                          uint32_t* sqpw, float* scalew) {
#pragma unroll
    for (int j = 0; j < 4; ++j) {
        int lr = j * 4 + q4;
        float s0 = sigf(qx[j].x), s1 = sigf(qx[j].y), s2 = sigf(qx[j].z), s3 = sigf(qx[j].w);
        float pa = (s0 + EPSF) * ksE.x + (s1 + EPSF) * ksE.y +
                   (s2 + EPSF) * ksE.z + (s3 + EPSF) * ksE.w;
        float pb = (s0 + EPSF) * knE.x + (s1 + EPSF) * knE.y +
                   (s2 + EPSF) * knE.z + (s3 + EPSF) * knE.w;
        pa = rowsum16(pa); pb = rowsum16(pb);
        float sc = __builtin_amdgcn_rcpf(pa) * sigf(pb) * sden;  // nrow*rref*S/den
        if (i16 == 0) scalew[lr] = sc;
        uint32_t* sp = &sqpw[lr * STRO + 4 * i16];
        *(uint4*)sp = make_uint4(packhl(s0), packhl(s1), packhl(s2), packhl(s3));
    }
}

// ---------------- P4: out = (SQ·KV) * nrow * rref * S/den via MFMA ----------------
__global__ __launch_bounds__(256, 4) void k_out(const float* __restrict__ Q,
                                                const float* __restrict__ ksum,
                                                const float* __restrict__ kn,
                                                const float* __restrict__ den,
                                                const float* __restrict__ KVg,
                                                float* __restrict__ out) {
    int bh = blockIdx.x, b = bh >> 4, h = bh & 15;
    int t = threadIdx.x, lane = t & 63, w = t >> 6;
    int q4 = lane >> 4, i16 = lane & 15;
    __shared__ uint32_t kvt[64 * STRO];        // packed KV^T: [e][d]
    __shared__ uint32_t sqp[4][16 * STRO];     // per-wave 16-row SQ staging
    __shared__ float scale_s[4][16];
    float4 ksE = *(const float4*)(ksum + bh * 64 + 4 * i16);
    float4 knE = *(const float4*)(kn + bh * 64 + 4 * i16);
    ksE.x += EPSF; ksE.y += EPSF; ksE.z += EPSF; ksE.w += EPSF;
    knE.x += EPSF; knE.y += EPSF; knE.z += EPSF; knE.w += EPSF;
    float sden = 4096.0f * __builtin_amdgcn_rcpf(den[bh]);
    int rowbase = blockIdx.y * 256;
    size_t base = (((size_t)b * L_) * H_ + h) * 64 + 4 * i16;
    const float* Qp = Q + base;
    // prologue Q loads for g=0 (overlap the kvt staging below)
    float4 qx[4];
#pragma unroll
    for (int j = 0; j < 4; ++j) {
        size_t r = (size_t)(rowbase + w * 64 + j * 4 + q4) * 1024;
        qx[j] = *(const float4*)(Qp + r);
    }
    // KV^T transpose-stage, float4 global loads
#pragma unroll
    for (int i = 0; i < 4; ++i) {
        int f4i = t + i * 256;
        float4 x = *(const float4*)(KVg + (size_t)bh * 4096 + 4 * f4i);
        int d = (4 * f4i) & 63, e = f4i >> 4;
        kvt[(d + 0) * STRO + e] = packhl(x.x);
        kvt[(d + 1) * STRO + e] = packhl(x.y);
        kvt[(d + 2) * STRO + e] = packhl(x.z);
        kvt[(d + 3) * STRO + e] = packhl(x.w);
    }
    __syncthreads();
#pragma unroll
    for (int g = 0; g < 4; ++g) {
        int r0 = rowbase + w * 64 + g * 16;
        // ---- stage this wave's 16 rows from registers (wave-private: no barrier)
        out_stage(qx, w, q4, i16, ksE, knE, sden, &sqp[w][0], &scale_s[w][0]);
        // ---- prefetch next group's Q: hides under MFMA below
        float4 qx2[4];
        if (g < 3) {
#pragma unroll
            for (int j = 0; j < 4; ++j) {
                size_t r = (size_t)(rowbase + w * 64 + (g + 1) * 16 + j * 4 + q4) * 1024;
                qx2[j] = *(const float4*)(Qp + r);
            }
        }
        f32x4 acc[4];
#pragma unroll
        for (int tn = 0; tn < 4; ++tn) acc[tn] = (f32x4){0.f, 0.f, 0.f, 0.f};
#pragma unroll
        for (int ks = 0; ks < 2; ++ks) {
            const uint32_t* ap = &sqp[w][i16 * STRO + 32 * ks + 8 * q4];
            uint4 a0 = *(const uint4*)ap, a1 = *(const uint4*)(ap + 4);
            uint32_t aw[8] = {a0.x, a0.y, a0.z, a0.w, a1.x, a1.y, a1.z, a1.w};
            bf16x8 ahi, alo; buildfrag(aw, ahi, alo);
#pragma unroll
            for (int tn = 0; tn < 4; ++tn) {
                const uint32_t* bp = &kvt[(16 * tn + i16) * STRO + 32 * ks + 8 * q4];
                uint4 b0 = *(const uint4*)bp, b1 = *(const uint4*)(bp + 4);
                uint32_t bw[8] = {b0.x, b0.y, b0.z, b0.w, b1.x, b1.y, b1.z, b1.w};
                bf16x8 bhi, blo; buildfrag(bw, bhi, blo);
                MFMA3(acc[tn], ahi, alo, bhi, blo);
            }
        }
#pragma unroll
        for (int tn = 0; tn < 4; ++tn)
#pragma unroll
            for (int r = 0; r < 4; ++r) {
                int rl = 4 * q4 + r;
                float sc = scale_s[w][rl];
                out[(((size_t)b * L_ + (r0 + rl)) * H_ + h) * 64 + 16 * tn + i16] =
                    acc[tn][r] * sc;
            }
        if (g < 3) {
#pragma unroll
            for (int j = 0; j < 4; ++j) qx[j] = qx2[j];
        }
    }
}

extern "C" void kernel_launch(void* const* d_in, const int* in_sizes, int n_in,
                              void* d_out, int out_size, void* d_ws, size_t ws_size,
                              hipStream_t stream) {
    const float* Q = (const float*)d_in[0];
    const float* K = (const float*)d_in[1];
    const float* V = (const float*)d_in[2];
    float* out = (float*)d_out;
    float* ws = (float*)d_ws;
    float* ksum = ws;            // 4096
    float* qsum = ws + 4096;     // 4096
    float* qn   = ws + 8192;     // 4096
    float* kn   = ws + 12288;    // 4096
    float* den  = ws + 16384;    // 64
    float* KVg  = ws + 16448;    // 64*64*64 = 262144
    float* KVp  = ws + 16448 + 262144;  // 16 slices * 262144 = 4194304

    // only the small reduction buffers need zeroing (KVp/KVg fully overwritten)
    hipMemsetAsync(d_ws, 0, 16448ull * 4ull, stream);
    k_ksum<<<dim3(64, 32), 256, 0, stream>>>(K, ksum);
    k_qpass<<<dim3(64, 32), 256, 0, stream>>>(Q, ksum, qsum, qn);
    k_kv<<<dim3(64, 16), 256, 0, stream>>>(K, V, qsum, qn, kn, den, KVp);
    k_reduce<<<dim3(64, 4), 256, 0, stream>>>(KVp, KVg);
    k_out<<<dim3(64, 16), 256, 0, stream>>>(Q, ksum, kn, den, KVg, out);
}

// Round 6
// 330.132 us; speedup vs baseline: 1.0382x; 1.0382x over previous
//
#include <hip/hip_runtime.h>
#include <math.h>
#include <stdint.h>

// FlowAttention B=4, L=S=4096, H=16, D=64 fp32.
// P1 ksum(K) -> P2 qsum,qn(Q) -> P3 kn,den,KV-partials via MFMA (K,V) -> reduce -> P4 out via MFMA (Q).
// GEMM-shaped contractions use bf16 hi/lo-split MFMA (3 mfma per tile-step, ~2^-16 rel err).
// R6: R4's scratch-spill fix WITHOUT any inline asm (the only construct R3 didn't run).
// In-body constant-index loads (SROA-able), __restrict__ stage params, by-value out_stage.
// If this also kills the container, the failure is infra, not source.
#define B_ 4
#define L_ 4096
#define H_ 16
#define EPSF 1e-6f
#define STR 66   // k_kv LDS row stride (words)
#define STRO 68  // k_out LDS row stride (words, 16B-aligned rows)

typedef short bf16x8 __attribute__((ext_vector_type(8)));
typedef float f32x4 __attribute__((ext_vector_type(4)));
union FragU { uint32_t u[4]; bf16x8 v; };

__device__ __forceinline__ float sigf(float x) { return 1.0f / (1.0f + __expf(-x)); }

// sum over each 16-lane row: quad xor1, quad xor2, row_ror:4, row_ror:8 (all full-rate VALU)
__device__ __forceinline__ float rowsum16(float v) {
    v += __int_as_float(__builtin_amdgcn_update_dpp(0, __float_as_int(v), 0xB1, 0xF, 0xF, true));
    v += __int_as_float(__builtin_amdgcn_update_dpp(0, __float_as_int(v), 0x4E, 0xF, 0xF, true));
    v += __int_as_float(__builtin_amdgcn_update_dpp(0, __float_as_int(v), 0x124, 0xF, 0xF, true));
    v += __int_as_float(__builtin_amdgcn_update_dpp(0, __float_as_int(v), 0x128, 0xF, 0xF, true));
    return v;
}

// pack fp32 -> (bf16 hi | bf16 lo) in one 32-bit word. hi = truncate-to-bf16, lo = x - hi.
__device__ __forceinline__ uint32_t packhl(float x) {
    uint32_t xb = __float_as_uint(x);
    uint32_t hb = xb & 0xFFFF0000u;
    float lo = x - __uint_as_float(hb);
    return (hb >> 16) | (__float_as_uint(lo) & 0xFFFF0000u);
}

// 8 packed words (k-order) -> hi and lo bf16x8 fragments via v_perm
__device__ __forceinline__ void buildfrag(const uint32_t w[8], bf16x8& hi, bf16x8& lo) {
    FragU H, L;
#pragma unroll
    for (int t = 0; t < 4; ++t) {
        H.u[t] = __builtin_amdgcn_perm(w[2 * t + 1], w[2 * t], 0x05040100u);
        L.u[t] = __builtin_amdgcn_perm(w[2 * t + 1], w[2 * t], 0x07060302u);
    }
    hi = H.v; lo = L.v;
}

#define MFMA3(acc, ahi, alo, bhi, blo)                                        \
    acc = __builtin_amdgcn_mfma_f32_16x16x32_bf16(ahi, bhi, acc, 0, 0, 0);    \
    acc = __builtin_amdgcn_mfma_f32_16x16x32_bf16(ahi, blo, acc, 0, 0, 0);    \
    acc = __builtin_amdgcn_mfma_f32_16x16x32_bf16(alo, bhi, acc, 0, 0, 0);

// in-body tile load (constant indices only -> SROA to registers; no helper pointers)
#define LOADTILE(kx, vx, tile)                                                 \
    do {                                                                       \
        _Pragma("unroll") for (int j_ = 0; j_ < 4; ++j_) {                     \
            size_t r_ = (size_t)(rowbase + (tile) * 64 + lrow + j_ * 4) * 1024; \
            kx[j_] = *(const float4*)(Kp + r_);                                \
            vx[j_] = *(const float4*)(Vp + r_);                                \
        }                                                                      \
    } while (0)

// ---------------- P1: ksum[d] = sum_s sigmoid(K) ----------------
__global__ __launch_bounds__(256, 6) void k_ksum(const float* __restrict__ K,
                                                 float* __restrict__ ksum) {
    int bh = blockIdx.x, b = bh >> 4, h = bh & 15;
    int t = threadIdx.x, lane = t & 63, w = t >> 6;
    int q4 = lane >> 4, i16 = lane & 15;
    int r0 = blockIdx.y * 128 + w * 32;
    float4 x[8];
#pragma unroll
    for (int j = 0; j < 8; ++j) {
        int r = r0 + j * 4 + q4;
        x[j] = *(const float4*)(K + (((size_t)b * L_ + r) * H_ + h) * 64 + 4 * i16);
    }
    float a0 = 0.f, a1 = 0.f, a2 = 0.f, a3 = 0.f;
#pragma unroll
    for (int j = 0; j < 8; ++j) {
        a0 += sigf(x[j].x); a1 += sigf(x[j].y);
        a2 += sigf(x[j].z); a3 += sigf(x[j].w);
    }
#pragma unroll
    for (int m = 16; m < 64; m <<= 1) {
        a0 += __shfl_xor(a0, m, 64); a1 += __shfl_xor(a1, m, 64);
        a2 += __shfl_xor(a2, m, 64); a3 += __shfl_xor(a3, m, 64);
    }
    if (q4 == 0) {
        atomicAdd(&ksum[bh * 64 + 4 * i16 + 0], a0);
        atomicAdd(&ksum[bh * 64 + 4 * i16 + 1], a1);
        atomicAdd(&ksum[bh * 64 + 4 * i16 + 2], a2);
        atomicAdd(&ksum[bh * 64 + 4 * i16 + 3], a3);
    }
}

// ---------------- P2: qsum[d], qn[d] ----------------
__global__ __launch_bounds__(256, 6) void k_qpass(const float* __restrict__ Q,
                                                  const float* __restrict__ ksum,
                                                  float* __restrict__ qsum,
                                                  float* __restrict__ qn) {
    int bh = blockIdx.x, b = bh >> 4, h = bh & 15;
    int t = threadIdx.x, lane = t & 63, w = t >> 6;
    int q4 = lane >> 4, i16 = lane & 15;
    int r0 = blockIdx.y * 128 + w * 32;
    float4 ks4 = *(const float4*)(ksum + bh * 64 + 4 * i16);
    ks4.x += EPSF; ks4.y += EPSF; ks4.z += EPSF; ks4.w += EPSF;
    float4 x[8];
#pragma unroll
    for (int j = 0; j < 8; ++j) {
        int r = r0 + j * 4 + q4;
        x[j] = *(const float4*)(Q + (((size_t)b * L_ + r) * H_ + h) * 64 + 4 * i16);
    }
    float qs0 = 0.f, qs1 = 0.f, qs2 = 0.f, qs3 = 0.f;
    float qa0 = 0.f, qa1 = 0.f, qa2 = 0.f, qa3 = 0.f;
#pragma unroll
    for (int j = 0; j < 8; ++j) {
        float s0 = sigf(x[j].x), s1 = sigf(x[j].y), s2 = sigf(x[j].z), s3 = sigf(x[j].w);
        float pa = (s0 + EPSF) * ks4.x + (s1 + EPSF) * ks4.y +
                   (s2 + EPSF) * ks4.z + (s3 + EPSF) * ks4.w;
        pa = rowsum16(pa);
        float nr = __builtin_amdgcn_rcpf(pa);
        qs0 += s0; qs1 += s1; qs2 += s2; qs3 += s3;
        qa0 += s0 * nr; qa1 += s1 * nr; qa2 += s2 * nr; qa3 += s3 * nr;
    }
#pragma unroll
    for (int m = 16; m < 64; m <<= 1) {
        qs0 += __shfl_xor(qs0, m, 64); qs1 += __shfl_xor(qs1, m, 64);
        qs2 += __shfl_xor(qs2, m, 64); qs3 += __shfl_xor(qs3, m, 64);
        qa0 += __shfl_xor(qa0, m, 64); qa1 += __shfl_xor(qa1, m, 64);
        qa2 += __shfl_xor(qa2, m, 64); qa3 += __shfl_xor(qa3, m, 64);
    }
    if (q4 == 0) {
        atomicAdd(&qsum[bh * 64 + 4 * i16 + 0], qs0);
        atomicAdd(&qsum[bh * 64 + 4 * i16 + 1], qs1);
        atomicAdd(&qsum[bh * 64 + 4 * i16 + 2], qs2);
        atomicAdd(&qsum[bh * 64 + 4 * i16 + 3], qs3);
        atomicAdd(&qn[bh * 64 + 4 * i16 + 0], qa0);
        atomicAdd(&qn[bh * 64 + 4 * i16 + 1], qa1);
        atomicAdd(&qn[bh * 64 + 4 * i16 + 2], qa2);
        atomicAdd(&qn[bh * 64 + 4 * i16 + 3], qa3);
    }
}

// ---- k_kv helpers (read-only params, __restrict__: SROA-safe) ----
__device__ __forceinline__ void kv_stage(const float4* __restrict__ kx,
                                         const float4* __restrict__ vx,
                                         int w, int q4, int i16,
                                         float4 qsE, float4 qnE,
                                         uint32_t* __restrict__ skp,
                                         uint32_t* __restrict__ vwp,
                                         float& kn0, float& kn1, float& kn2, float& kn3,
                                         float& dacc) {
#pragma unroll
    for (int j = 0; j < 4; ++j) {
        int lr = w * 16 + j * 4 + q4;
        float s0 = sigf(kx[j].x), s1 = sigf(kx[j].y), s2 = sigf(kx[j].z), s3 = sigf(kx[j].w);
        float pa = (s0 + EPSF) * qsE.x + (s1 + EPSF) * qsE.y +
                   (s2 + EPSF) * qsE.z + (s3 + EPSF) * qsE.w;
        float pc = (s0 + EPSF) * qnE.x + (s1 + EPSF) * qnE.y +
                   (s2 + EPSF) * qnE.z + (s3 + EPSF) * qnE.w;
        pa = rowsum16(pa); pc = rowsum16(pc);
        float ncol = __builtin_amdgcn_rcpf(pa);
        float es = __expf(pc);                 // logits O(1): no max-subtract needed
        kn0 += s0 * ncol; kn1 += s1 * ncol; kn2 += s2 * ncol; kn3 += s3 * ncol;
        if (i16 == 0) dacc += es;
        uint32_t* sp = &skp[lr * STR + 4 * i16];
        *(uint2*)sp = make_uint2(packhl(s0), packhl(s1));
        *(uint2*)(sp + 2) = make_uint2(packhl(s2), packhl(s3));
        uint32_t* vp = &vwp[lr * STR + 4 * i16];
        *(uint2*)vp = make_uint2(packhl(vx[j].x * es), packhl(vx[j].y * es));
        *(uint2*)(vp + 2) = make_uint2(packhl(vx[j].z * es), packhl(vx[j].w * es));
    }
}

__device__ __forceinline__ void kv_mfma(const uint32_t* __restrict__ skp,
                                        const uint32_t* __restrict__ vwp,
                                        int q4, int i16, int td0, int te0, f32x4* acc) {
#pragma unroll
    for (int ks = 0; ks < 2; ++ks) {
        bf16x8 bhi[2], blo[2];
#pragma unroll
        for (int tn = 0; tn < 2; ++tn) {
            uint32_t bw[8];
#pragma unroll
            for (int j = 0; j < 8; ++j)
                bw[j] = vwp[(32 * ks + 8 * q4 + j) * STR + 16 * (te0 + tn) + i16];
            buildfrag(bw, bhi[tn], blo[tn]);
        }
#pragma unroll
        for (int tm = 0; tm < 2; ++tm) {
            uint32_t aw[8];
#pragma unroll
            for (int j = 0; j < 8; ++j)
                aw[j] = skp[(32 * ks + 8 * q4 + j) * STR + 16 * (td0 + tm) + i16];
            bf16x8 ahi, alo; buildfrag(aw, ahi, alo);
#pragma unroll
            for (int tn = 0; tn < 2; ++tn) {
                MFMA3(acc[tm * 2 + tn], ahi, alo, bhi[tn], blo[tn]);
            }
        }
    }
}

// ---------------- P3: kn, den, KV-partials via MFMA ----------------
__global__ __launch_bounds__(256, 4) void k_kv(const float* __restrict__ K,
                                               const float* __restrict__ V,
                                               const float* __restrict__ qsum,
                                               const float* __restrict__ qn,
                                               float* __restrict__ kn,
                                               float* __restrict__ den,
                                               float* __restrict__ KVp) {
    int bh = blockIdx.x, b = bh >> 4, h = bh & 15;
    int t = threadIdx.x, lane = t & 63, w = t >> 6;
    int q4 = lane >> 4, i16 = lane & 15;
    int td0 = (w >> 1) * 2, te0 = (w & 1) * 2;   // 2x2 output tiles per wave
    __shared__ uint32_t skp[64 * STR];
    __shared__ uint32_t vwp[64 * STR];
    float4 qsE = *(const float4*)(qsum + bh * 64 + 4 * i16);
    float4 qnE = *(const float4*)(qn + bh * 64 + 4 * i16);
    qsE.x += EPSF; qsE.y += EPSF; qsE.z += EPSF; qsE.w += EPSF;
    qnE.x += EPSF; qnE.y += EPSF; qnE.z += EPSF; qnE.w += EPSF;
    f32x4 acc[4];
#pragma unroll
    for (int tm = 0; tm < 4; ++tm) acc[tm] = (f32x4){0.f, 0.f, 0.f, 0.f};
    float kn0 = 0.f, kn1 = 0.f, kn2 = 0.f, kn3 = 0.f, dacc = 0.f;
    int rowbase = blockIdx.y * 256;
    size_t base = (((size_t)b * L_) * H_ + h) * 64 + 4 * i16;
    const float* Kp = K + base;
    const float* Vp = V + base;
    int lrow = w * 16 + q4;   // this lane's first staged row offset within a tile

    float4 kA[4], vA[4], kB[4], vB[4];
    // distance-1 alternating register buffers, loads issued at tile-top.
    LOADTILE(kA, vA, 0);
    // tile 0
    LOADTILE(kB, vB, 1);
    kv_stage(kA, vA, w, q4, i16, qsE, qnE, skp, vwp, kn0, kn1, kn2, kn3, dacc);
    __syncthreads();
    kv_mfma(skp, vwp, q4, i16, td0, te0, acc);
    __syncthreads();
    // tile 1
    LOADTILE(kA, vA, 2);
    kv_stage(kB, vB, w, q4, i16, qsE, qnE, skp, vwp, kn0, kn1, kn2, kn3, dacc);
    __syncthreads();
    kv_mfma(skp, vwp, q4, i16, td0, te0, acc);
    __syncthreads();
    // tile 2
    LOADTILE(kB, vB, 3);
    kv_stage(kA, vA, w, q4, i16, qsE, qnE, skp, vwp, kn0, kn1, kn2, kn3, dacc);
    __syncthreads();
    kv_mfma(skp, vwp, q4, i16, td0, te0, acc);
    __syncthreads();
    // tile 3
    kv_stage(kB, vB, w, q4, i16, qsE, qnE, skp, vwp, kn0, kn1, kn2, kn3, dacc);
    __syncthreads();
    kv_mfma(skp, vwp, q4, i16, td0, te0, acc);

    // ---- KV partial: plain stores (no atomics); slice = blockIdx.y
    // D[m=d][n=e], row=(lane>>4)*4+reg, col=lane&15 (m89-verified)
    float* kvslice = KVp + ((size_t)blockIdx.y * 64 + bh) * 4096;
#pragma unroll
    for (int tm = 0; tm < 2; ++tm)
#pragma unroll
        for (int tn = 0; tn < 2; ++tn)
#pragma unroll
            for (int r = 0; r < 4; ++r)
                kvslice[(16 * (td0 + tm) + 4 * q4 + r) * 64 + 16 * (te0 + tn) + i16] =
                    acc[tm * 2 + tn][r];
#pragma unroll
    for (int m = 16; m < 64; m <<= 1) {
        kn0 += __shfl_xor(kn0, m, 64); kn1 += __shfl_xor(kn1, m, 64);
        kn2 += __shfl_xor(kn2, m, 64); kn3 += __shfl_xor(kn3, m, 64);
    }
    if (q4 == 0) {
        atomicAdd(&kn[bh * 64 + 4 * i16 + 0], kn0);
        atomicAdd(&kn[bh * 64 + 4 * i16 + 1], kn1);
        atomicAdd(&kn[bh * 64 + 4 * i16 + 2], kn2);
        atomicAdd(&kn[bh * 64 + 4 * i16 + 3], kn3);
    }
#pragma unroll
    for (int m = 1; m < 64; m <<= 1) dacc += __shfl_xor(dacc, m, 64);
    if (lane == 0) atomicAdd(&den[bh], dacc);
}

// ---------------- P3b: KVg = sum over 16 partial slices ----------------
__global__ __launch_bounds__(256) void k_reduce(const float* __restrict__ KVp,
                                                float* __restrict__ KVg) {
    int bh = blockIdx.x;            // 64
    int f4 = blockIdx.y * 256 + threadIdx.x;  // float4 index in [0,1024)
    float4 acc = make_float4(0.f, 0.f, 0.f, 0.f);
#pragma unroll
    for (int p = 0; p < 16; ++p) {
        float4 x = *(const float4*)(KVp + ((size_t)p * 64 + bh) * 4096 + 4 * f4);
        acc.x += x.x; acc.y += x.y; acc.z += x.z; acc.w += x.w;
    }
    *(float4*)(KVg + (size_t)bh * 4096 + 4 * f4) = acc;
}

// ---- k_out helpers (by-value float4s: no pointer aliasing, SROA-safe) ----
__device__ __forceinline__ void out_stage(float4 x0, float4 x1, float4 x2, float4 x3,
                                          int w, int q4, int i16,
                                          float4 ksE, float4 knE, float sden,
                                          uint32_t* __restrict__ sqpw,
                                          float* __restrict__ scalew) {
    float4 qv[4] = {x0, x1, x2, x3};
#pragma unroll
    for (int j = 0; j < 4; ++j) {
        int lr = j * 4 + q4;
        float s0 = sigf(qv[j].x), s1 = sigf(qv[j].y), s2 = sigf(qv[j].z), s3 = sigf(qv[j].w);
        float pa = (s0 + EPSF) * ksE.x + (s1 + EPSF) * ksE.y +
                   (s2 + EPSF) * ksE.z + (s3 + EPSF) * ksE.w;
        float pb = (s0 + EPSF) * knE.x + (s1 + EPSF) * knE.y +
                   (s2 + EPSF) * knE.z + (s3 + EPSF) * knE.w;
        pa = rowsum16(pa); pb = rowsum16(pb);
        float sc = __builtin_amdgcn_rcpf(pa) * sigf(pb) * sden;  // nrow*rref*S/den
        if (i16 == 0) scalew[lr] = sc;
        uint32_t* sp = &sqpw[lr * STRO + 4 * i16];
        *(uint4*)sp = make_uint4(packhl(s0), packhl(s1), packhl(s2), packhl(s3));
    }
}

// ---------------- P4: out = (SQ·KV) * nrow * rref * S/den via MFMA ----------------
__global__ __launch_bounds__(256, 4) void k_out(const float* __restrict__ Q,
                                                const float* __restrict__ ksum,
                                                const float* __restrict__ kn,
                                                const float* __restrict__ den,
                                                const float* __restrict__ KVg,
                                                float* __restrict__ out) {
    int bh = blockIdx.x, b = bh >> 4, h = bh & 15;
    int t = threadIdx.x, lane = t & 63, w = t >> 6;
    int q4 = lane >> 4, i16 = lane & 15;
    __shared__ uint32_t kvt[64 * STRO];        // packed KV^T: [e][d]
    __shared__ uint32_t sqp[4][16 * STRO];     // per-wave 16-row SQ staging
    __shared__ float scale_s[4][16];
    float4 ksE = *(const float4*)(ksum + bh * 64 + 4 * i16);
    float4 knE = *(const float4*)(kn + bh * 64 + 4 * i16);
    ksE.x += EPSF; ksE.y += EPSF; ksE.z += EPSF; ksE.w += EPSF;
    knE.x += EPSF; knE.y += EPSF; knE.z += EPSF; knE.w += EPSF;
    float sden = 4096.0f * __builtin_amdgcn_rcpf(den[bh]);
    int rowbase = blockIdx.y * 256;
    size_t base = (((size_t)b * L_) * H_ + h) * 64 + 4 * i16;
    const float* Qp = Q + base;
    // prologue Q loads for g=0 (overlap the kvt staging below)
    float4 qx[4];
#pragma unroll
    for (int j = 0; j < 4; ++j) {
        size_t r = (size_t)(rowbase + w * 64 + j * 4 + q4) * 1024;
        qx[j] = *(const float4*)(Qp + r);
    }
    // KV^T transpose-stage, float4 global loads
#pragma unroll
    for (int i = 0; i < 4; ++i) {
        int f4i = t + i * 256;
        float4 x = *(const float4*)(KVg + (size_t)bh * 4096 + 4 * f4i);
        int d = (4 * f4i) & 63, e = f4i >> 4;
        kvt[(d + 0) * STRO + e] = packhl(x.x);
        kvt[(d + 1) * STRO + e] = packhl(x.y);
        kvt[(d + 2) * STRO + e] = packhl(x.z);
        kvt[(d + 3) * STRO + e] = packhl(x.w);
    }
    __syncthreads();
#pragma unroll
    for (int g = 0; g < 4; ++g) {
        int r0 = rowbase + w * 64 + g * 16;
        // ---- stage this wave's 16 rows from registers (wave-private: no barrier)
        out_stage(qx[0], qx[1], qx[2], qx[3], w, q4, i16, ksE, knE, sden,
                  &sqp[w][0], &scale_s[w][0]);
        // ---- prefetch next group's Q
        float4 qx2[4];
        if (g < 3) {
#pragma unroll
            for (int j = 0; j < 4; ++j) {
                size_t r = (size_t)(rowbase + w * 64 + (g + 1) * 16 + j * 4 + q4) * 1024;
                qx2[j] = *(const float4*)(Qp + r);
            }
        }
        f32x4 acc[4];
#pragma unroll
        for (int tn = 0; tn < 4; ++tn) acc[tn] = (f32x4){0.f, 0.f, 0.f, 0.f};
#pragma unroll
        for (int ks = 0; ks < 2; ++ks) {
            const uint32_t* ap = &sqp[w][i16 * STRO + 32 * ks + 8 * q4];
            uint4 a0 = *(const uint4*)ap, a1 = *(const uint4*)(ap + 4);
            uint32_t aw[8] = {a0.x, a0.y, a0.z, a0.w, a1.x, a1.y, a1.z, a1.w};
            bf16x8 ahi, alo; buildfrag(aw, ahi, alo);
#pragma unroll
            for (int tn = 0; tn < 4; ++tn) {
                const uint32_t* bp = &kvt[(16 * tn + i16) * STRO + 32 * ks + 8 * q4];
                uint4 b0 = *(const uint4*)bp, b1 = *(const uint4*)(bp + 4);
                uint32_t bw[8] = {b0.x, b0.y, b0.z, b0.w, b1.x, b1.y, b1.z, b1.w};
                bf16x8 bhi, blo; buildfrag(bw, bhi, blo);
                MFMA3(acc[tn], ahi, alo, bhi, blo);
            }
        }
#pragma unroll
        for (int tn = 0; tn < 4; ++tn)
#pragma unroll
            for (int r = 0; r < 4; ++r) {
                int rl = 4 * q4 + r;
                float sc = scale_s[w][rl];
                out[(((size_t)b * L_ + (r0 + rl)) * H_ + h) * 64 + 16 * tn + i16] =
                    acc[tn][r] * sc;
            }
        if (g < 3) {
#pragma unroll
            for (int j = 0; j < 4; ++j) qx[j] = qx2[j];
        }
    }
}

extern "C" void kernel_launch(void* const* d_in, const int* in_sizes, int n_in,
                              void* d_out, int out_size, void* d_ws, size_t ws_size,
                              hipStream_t stream) {
    const float* Q = (const float*)d_in[0];
    const float* K = (const float*)d_in[1];
    const float* V = (const float*)d_in[2];
    float* out = (float*)d_out;
    float* ws = (float*)d_ws;
    float* ksum = ws;            // 4096
    float* qsum = ws + 4096;     // 4096
    float* qn   = ws + 8192;     // 4096
    float* kn   = ws + 12288;    // 4096
    float* den  = ws + 16384;    // 64
    float* KVg  = ws + 16448;    // 64*64*64 = 262144
    float* KVp  = ws + 16448 + 262144;  // 16 slices * 262144 = 4194304

    // only the small reduction buffers need zeroing (KVp/KVg fully overwritten)
    hipMemsetAsync(d_ws, 0, 16448ull * 4ull, stream);
    k_ksum<<<dim3(64, 32), 256, 0, stream>>>(K, ksum);
    k_qpass<<<dim3(64, 32), 256, 0, stream>>>(Q, ksum, qsum, qn);
    k_kv<<<dim3(64, 16), 256, 0, stream>>>(K, V, qsum, qn, kn, den, KVp);
    k_reduce<<<dim3(64, 4), 256, 0, stream>>>(KVp, KVg);
    k_out<<<dim3(64, 16), 256, 0, stream>>>(Q, ksum, kn, den, KVg, out);
}